// Round 7
// baseline (555.244 us; speedup 1.0000x reference)
//
#include <hip/hip_runtime.h>
#include <hip/hip_bf16.h>

typedef __attribute__((ext_vector_type(4))) float f32x4;
typedef __attribute__((ext_vector_type(8))) short short8;

#define B_   32
#define S_   2048
#define H_   1024
#define D2_  2048   // 2H
#define BM   256
#define BN   256
#define BK   64
#define NKT  32        // D2_/BK
#define TILE_SH 16384  // shorts per 256x64 tile (32 KB)

// In-tile layout (keys_bf and uab_t): [kh(2)][row(256)][slot(4)] 16B units.
// Slot s' holds k-quarter q = s' ^ ((row>>1)&3); element k = kh*32 + q*8 + e.

// RNE f32 -> bf16
__device__ __forceinline__ short f2bf(float f) {
  unsigned u = __float_as_uint(f);
  u = (u + 0x7fffu + ((u >> 16) & 1u)) >> 16;
  return (short)u;
}

__device__ __forceinline__ short8 cvt8(f32x4 a, f32x4 b) {
  short8 o;
  o[0] = f2bf(a.x); o[1] = f2bf(a.y); o[2] = f2bf(a.z); o[3] = f2bf(a.w);
  o[4] = f2bf(b.x); o[5] = f2bf(b.y); o[6] = f2bf(b.z); o[7] = f2bf(b.w);
  return o;
}

// tanh via hardware exp2: tanh(x) = 1 - 2/(2^(2x*log2e)+1). Correct limits at +-inf.
__device__ __forceinline__ float fast_tanh(float x) {
  float e = __builtin_amdgcn_exp2f(x * 2.885390081777927f);
  return 1.0f - 2.0f * __builtin_amdgcn_rcpf(e + 1.0f);
}

__device__ __forceinline__ void gload16(const short* g, short* l) {
  __builtin_amdgcn_global_load_lds((const __attribute__((address_space(1))) void*)g,
                                   (__attribute__((address_space(3))) void*)l, 16, 0, 0);
}

// ---------------- kernel 1a: Ua_w f32 -> bf16 tile image ([nt(4)][kt(32)] tiles) ----------------
__global__ void k_convert_ua(const float* __restrict__ src, short* __restrict__ dst) {
  int idx = blockIdx.x * 256 + threadIdx.x;    // 262144 x 16B units
  int wu  = idx & 2047;
  int kt  = (idx >> 11) & 31;
  int nt  = idx >> 16;
  int kh  = wu >> 10;
  int row = (wu >> 2) & 255;
  int sl  = wu & 3;
  int q   = sl ^ ((row >> 1) & 3);
  const float* s = src + (size_t)(nt * 256 + row) * D2_ + kt * 64 + kh * 32 + q * 8;
  f32x4 a = *(const f32x4*)s;
  f32x4 b = *(const f32x4*)(s + 4);
  *(short8*)(dst + (size_t)idx * 8) = cvt8(a, b);
}

// ---------------- kernel 1b: keys f32 -> bf16 tile image ([mt(256)][kt(32)] tiles) ----------------
__global__ void k_convert_keys(const float* __restrict__ src, short* __restrict__ dst) {
  int idx = blockIdx.x * 256 + threadIdx.x;    // 16777216 x 16B units (grid 65536)
  int wu  = idx & 2047;
  int kt  = (idx >> 11) & 31;
  int mt  = idx >> 16;                         // 0..255
  int kh  = wu >> 10;
  int row = (wu >> 2) & 255;
  int sl  = wu & 3;
  int q   = sl ^ ((row >> 1) & 3);
  const float* s = src + (size_t)(mt * 256 + row) * D2_ + kt * 64 + kh * 32 + q * 8;
  f32x4 a = *(const f32x4*)s;
  f32x4 b = *(const f32x4*)(s + 4);
  *(short8*)(dst + (size_t)idx * 8) = cvt8(a, b);
}

// ---------------- kernel 2: wqb[b][h] = q[b] . Wa_w[h] + Wa_b[h] + Ua_b[h] ----------------
__global__ void k_wq(const float* __restrict__ query, const float* __restrict__ Wa_w,
                     const float* __restrict__ Wa_b, const float* __restrict__ Ua_b,
                     float* __restrict__ wqb) {
  int b = blockIdx.x;       // 32
  int hc = blockIdx.y;      // 8
  int t = threadIdx.x;      // 256
  __shared__ float q[H_];
  for (int i = t; i < H_; i += 256) q[i] = query[(size_t)b * (4 * H_) + 3 * H_ + i];
  __syncthreads();
  int h = hc * 128 + (t >> 1);
  int kh = (t & 1) * 512;
  const float* wr = Wa_w + (size_t)h * H_ + kh;
  float acc = 0.f;
  #pragma unroll 8
  for (int k = 0; k < 512; k += 4) {
    f32x4 wv = *(const f32x4*)(wr + k);
    acc += wv.x * q[kh + k] + wv.y * q[kh + k + 1] + wv.z * q[kh + k + 2] + wv.w * q[kh + k + 3];
  }
  acc += __shfl_xor(acc, 1);
  if ((t & 1) == 0) wqb[b * H_ + h] = acc + Wa_b[h] + Ua_b[h];
}

// ---------------- kernel 3: fused GEMM (keys @ Ua^T) + tanh + Va-reduce ----------------
// Software-pipelined 4-phase K-loop: ds_reads issued in phase i feed the MFMA of phase
// i+1; the wait before each MFMA is lgkmcnt(#reads just issued) (FIFO -> previous
// phase's reads drained), so LDS reads overlap MFMA continuously. Counted vmcnt(2)
// twice per K-tile, placed before the barrier that precedes any fresh-buffer ds_read.
#define MCL(mb, AF, BF)                                                                           \
  __builtin_amdgcn_s_setprio(1);                                                                  \
  _Pragma("unroll")                                                                               \
  for (int n = 0; n < 4; ++n) {                                                                   \
    _Pragma("unroll")                                                                             \
    for (int i = 0; i < 4; ++i)                                                                   \
      acc[(mb) + i][n] =                                                                          \
          __builtin_amdgcn_mfma_f32_16x16x32_bf16(AF[i], BF[n], acc[(mb) + i][n], 0, 0, 0);       \
  }                                                                                               \
  __builtin_amdgcn_s_setprio(0);

#define LGKM4  asm volatile("s_waitcnt lgkmcnt(4)" ::: "memory"); __builtin_amdgcn_sched_barrier(0);
#define LGKM8  asm volatile("s_waitcnt lgkmcnt(8)" ::: "memory"); __builtin_amdgcn_sched_barrier(0);
#define LGKM0  asm volatile("s_waitcnt lgkmcnt(0)" ::: "memory"); __builtin_amdgcn_sched_barrier(0);
#define VM2    asm volatile("s_waitcnt vmcnt(2)" ::: "memory");
#define VM0    asm volatile("s_waitcnt vmcnt(0)" ::: "memory");
#define BAR    __builtin_amdgcn_s_barrier();
#define SBAR0  __builtin_amdgcn_sched_barrier(0);

__global__ __launch_bounds__(512, 2) void k_gemm_score(
    const short* __restrict__ keys_bf, const short* __restrict__ uab_t,
    const float* __restrict__ wqb, const float* __restrict__ va,
    float* __restrict__ scores_p) {
  __shared__ short As[2][TILE_SH];   // 2 x 32 KB
  __shared__ short Bs[2][TILE_SH];   // 2 x 32 KB

  // bijective XCD swizzle: the 4 nt-blocks of an mt adjacent on one XCD
  const int bid = blockIdx.x;
  const int g = (bid & 7) * 128 + (bid >> 3);
  const int mt = g >> 2;               // 0..255
  const int nt = g & 3;                // 0..3
  const int r0 = mt * BM;
  const int h0 = nt * BN;

  const int t = threadIdx.x;
  const int lane = t & 63;
  const int w = t >> 6;
  const int wm = w >> 2;               // 0..1 (128-row half)
  const int wn = w & 3;                // 0..3 (64-col quarter)

  f32x4 acc[8][4] = {};

  const short* abase = keys_bf + (size_t)mt * (NKT * TILE_SH) + t * 8;
  const short* bbase = uab_t  + (size_t)nt * (NKT * TILE_SH) + t * 8;
  const int wu = w * 512;              // wave-uniform shorts within a 4096-short batch

  // fragment read offsets (shorts): + ks*8192 + m*512
  const int lr = lane & 15;
  const int lq = lane >> 4;
  const int slot = lq ^ ((lr >> 1) & 3);
  const int ar_ = (wm * 128 + lr) * 32 + slot * 8;
  const int br_ = (wn * 64 + lr) * 32 + slot * 8;

  short8 afX[4], afY[4], bfX[4], bfY[4];

  // ---- prologue: stage tile 0 fully; read F0(tile0) = {bf ks0, af m0-3 ks0} ----
  {
    #pragma unroll
    for (int j = 0; j < 4; ++j) gload16(abase + j * 4096, &As[0][j * 4096 + wu]);
    #pragma unroll
    for (int j = 0; j < 4; ++j) gload16(bbase + j * 4096, &Bs[0][j * 4096 + wu]);
    VM0
    BAR
    SBAR0
    #pragma unroll
    for (int n = 0; n < 4; ++n) bfX[n] = *(const short8*)&Bs[0][br_ + n * 512];
    #pragma unroll
    for (int i = 0; i < 4; ++i) afX[i] = *(const short8*)&As[0][ar_ + i * 512];
  }

  #pragma unroll 1
  for (int kt = 0; kt < NKT - 1; ++kt) {
    const int cb = kt & 1;
    const short* Ac = As[cb];
    const short* Bc = Bs[cb];
    const short* Anb = &As[cb ^ 1][0];
    const short* Bnb = &Bs[cb ^ 1][0];
    short* Anbw = &As[cb ^ 1][0];
    short* Bnbw = &Bs[cb ^ 1][0];
    const short* anext = abase + (size_t)(kt + 1) * TILE_SH;
    const short* bnext = bbase + (size_t)(kt + 1) * TILE_SH;

    // ---- P0: read F1(cur)=af m4-7 ks0 -> afY; gload A-k0(nxt); M0 = afX x bfX ----
    #pragma unroll
    for (int i = 0; i < 4; ++i) afY[i] = *(const short8*)&Ac[ar_ + (4 + i) * 512];
    gload16(anext + 0 * 4096, Anbw + 0 * 4096 + wu);
    gload16(anext + 1 * 4096, Anbw + 1 * 4096 + wu);
    BAR
    LGKM4
    MCL(0, afX, bfX)
    VM2                 // drain A-k1,B-k1 of cur (issued P2/P3 prev) before P1 reads ks1
    BAR
    SBAR0

    // ---- P1: read F2(cur)={bf ks1, af m0-3 ks1} -> bfY,afX; gload B-k0(nxt); M1 ----
    #pragma unroll
    for (int n = 0; n < 4; ++n) bfY[n] = *(const short8*)&Bc[br_ + 8192 + n * 512];
    #pragma unroll
    for (int i = 0; i < 4; ++i) afX[i] = *(const short8*)&Ac[ar_ + 8192 + i * 512];
    gload16(bnext + 0 * 4096, Bnbw + 0 * 4096 + wu);
    gload16(bnext + 1 * 4096, Bnbw + 1 * 4096 + wu);
    BAR
    LGKM8
    MCL(4, afY, bfX)
    BAR

    // ---- P2: read F3(cur)=af m4-7 ks1 -> afY; gload A-k1(nxt); M2 ----
    #pragma unroll
    for (int i = 0; i < 4; ++i) afY[i] = *(const short8*)&Ac[ar_ + 8192 + (4 + i) * 512];
    gload16(anext + 2 * 4096, Anbw + 2 * 4096 + wu);
    gload16(anext + 3 * 4096, Anbw + 3 * 4096 + wu);
    BAR
    LGKM4
    MCL(0, afX, bfY)
    VM2                 // drain A-k0,B-k0 of nxt before P3 reads next tile's ks0
    BAR
    SBAR0

    // ---- P3: read F0(nxt)={bf ks0, af m0-3 ks0} -> bfX,afX; gload B-k1(nxt); M3 ----
    #pragma unroll
    for (int n = 0; n < 4; ++n) bfX[n] = *(const short8*)&Bnb[br_ + n * 512];
    #pragma unroll
    for (int i = 0; i < 4; ++i) afX[i] = *(const short8*)&Anb[ar_ + i * 512];
    gload16(bnext + 2 * 4096, Bnbw + 2 * 4096 + wu);
    gload16(bnext + 3 * 4096, Bnbw + 3 * 4096 + wu);
    BAR
    LGKM8
    MCL(4, afY, bfY)
    BAR
  }

  // ---- epilogue tile (kt = NKT-1, buffer 1), no staging ----
  {
    const short* Ac = As[1];
    const short* Bc = Bs[1];
    // E-P0
    #pragma unroll
    for (int i = 0; i < 4; ++i) afY[i] = *(const short8*)&Ac[ar_ + (4 + i) * 512];
    BAR
    LGKM4
    MCL(0, afX, bfX)
    VM0                 // last tile's ks1 halves must be fully landed
    BAR
    SBAR0
    // E-P1
    #pragma unroll
    for (int n = 0; n < 4; ++n) bfY[n] = *(const short8*)&Bc[br_ + 8192 + n * 512];
    #pragma unroll
    for (int i = 0; i < 4; ++i) afX[i] = *(const short8*)&Ac[ar_ + 8192 + i * 512];
    BAR
    LGKM8
    MCL(4, afY, bfX)
    BAR
    // E-P2
    #pragma unroll
    for (int i = 0; i < 4; ++i) afY[i] = *(const short8*)&Ac[ar_ + 8192 + (4 + i) * 512];
    BAR
    LGKM4
    MCL(0, afX, bfY)
    BAR
    // E-P3
    LGKM0
    MCL(4, afY, bfY)
  }

  // ---- epilogue: tanh + Va-weighted row-reduce ----
  // C/D layout: col = lane&15, row = (lane>>4)*4 + reg
  const int lgrp = lane >> 4;
  const int lc = lane & 15;
  float vah[4];
  #pragma unroll
  for (int n = 0; n < 4; ++n) vah[n] = va[h0 + wn * 64 + n * 16 + lc];
  #pragma unroll
  for (int m = 0; m < 8; ++m) {
    #pragma unroll
    for (int reg = 0; reg < 4; ++reg) {
      int row = wm * 128 + m * 16 + lgrp * 4 + reg;
      int r = r0 + row;
      int bb = r & (B_ - 1);
      const float* wrow = wqb + bb * H_ + h0 + wn * 64 + lc;
      float s = 0.f;
      #pragma unroll
      for (int n = 0; n < 4; ++n)
        s += vah[n] * fast_tanh(acc[m][n][reg] + wrow[n * 16]);
      s += __shfl_xor(s, 1);
      s += __shfl_xor(s, 2);
      s += __shfl_xor(s, 4);
      s += __shfl_xor(s, 8);
      if (lc == 0) scores_p[(size_t)r * 16 + nt * 4 + wn] = s;
    }
  }
}

// ---------------- fallback GEMM (reg-staged A; used only when ws too small) ----------------
__global__ __launch_bounds__(512, 2) void k_gemm_rs(
    const float* __restrict__ keys, const short* __restrict__ uab_t,
    const float* __restrict__ wqb, const float* __restrict__ va,
    float* __restrict__ scores_p) {
  __shared__ short As[2][TILE_SH];
  __shared__ short Bs[2][TILE_SH];
  const int bid = blockIdx.x;
  const int g = (bid & 7) * 128 + (bid >> 3);
  const int mt = g >> 2;
  const int nt = g & 3;
  const int r0 = mt * BM;
  const int h0 = nt * BN;
  const int t = threadIdx.x;
  const int lane = t & 63;
  const int w = t >> 6;
  const int wm = w >> 2;
  const int wn = w & 3;
  f32x4 acc[8][4] = {};
  const int arow = t >> 1;
  const int ahalf = t & 1;
  const float* abase = keys + (size_t)(r0 + arow) * D2_ + ahalf * 32;
  int awoff[4];
  #pragma unroll
  for (int j = 0; j < 4; ++j)
    awoff[j] = (ahalf * 1024 + arow * 4 + (j ^ ((arow >> 1) & 3))) * 8;
  const short* bbase = uab_t + (size_t)nt * NKT * TILE_SH + t * 8;
  const int wu = w * 512;
  const int lr = lane & 15;
  const int lq = lane >> 4;
  const int slot = lq ^ ((lr >> 1) & 3);
  const int ar_ = (wm * 128 + lr) * 32 + slot * 8;
  const int br_ = (wn * 64 + lr) * 32 + slot * 8;
  short8 af[4], bf[4];
  {
    f32x4 v[8];
    #pragma unroll
    for (int j = 0; j < 8; ++j) v[j] = *(const f32x4*)(abase + j * 4);
    #pragma unroll
    for (int j = 0; j < 4; ++j)
      *(short8*)&As[0][awoff[j]] = cvt8(v[2 * j], v[2 * j + 1]);
    #pragma unroll
    for (int j = 0; j < 4; ++j) gload16(bbase + j * 4096, &Bs[0][j * 4096 + wu]);
    asm volatile("s_waitcnt vmcnt(0) lgkmcnt(0)" ::: "memory");
    __builtin_amdgcn_s_barrier();
  }
  f32x4 av[8];
  #pragma unroll 1
  for (int kt = 0; kt < NKT; ++kt) {
    const int cb = kt & 1;
    const bool stage = (kt < NKT - 1);
    const float* anext = abase + (kt + 1) * BK;
    const short* bnext = bbase + (size_t)(kt + 1) * TILE_SH;
    short* Bnb = &Bs[cb ^ 1][0];
    const short* Ac = As[cb];
    const short* Bc = Bs[cb];

    #pragma unroll
    for (int n = 0; n < 4; ++n) bf[n] = *(const short8*)&Bc[br_ + n * 512];
    #pragma unroll
    for (int i = 0; i < 4; ++i) af[i] = *(const short8*)&Ac[ar_ + i * 512];
    if (stage) {
      #pragma unroll
      for (int j = 0; j < 8; ++j) av[j] = *(const f32x4*)(anext + j * 4);
    }
    __builtin_amdgcn_s_barrier();
    LGKM0
    MCL(0, af, bf)
    __builtin_amdgcn_s_barrier();

    #pragma unroll
    for (int i = 0; i < 4; ++i) af[i] = *(const short8*)&Ac[ar_ + (4 + i) * 512];
    if (stage) {
      gload16(bnext + 0 * 4096, Bnb + 0 * 4096 + wu);
      gload16(bnext + 1 * 4096, Bnb + 1 * 4096 + wu);
    }
    __builtin_amdgcn_s_barrier();
    LGKM0
    MCL(4, af, bf)
    __builtin_amdgcn_s_barrier();

    #pragma unroll
    for (int n = 0; n < 4; ++n) bf[n] = *(const short8*)&Bc[br_ + 8192 + n * 512];
    #pragma unroll
    for (int i = 0; i < 4; ++i) af[i] = *(const short8*)&Ac[ar_ + 8192 + i * 512];
    if (stage) {
      gload16(bnext + 2 * 4096, Bnb + 2 * 4096 + wu);
      gload16(bnext + 3 * 4096, Bnb + 3 * 4096 + wu);
    }
    __builtin_amdgcn_s_barrier();
    LGKM0
    MCL(0, af, bf)
    __builtin_amdgcn_s_barrier();

    #pragma unroll
    for (int i = 0; i < 4; ++i) af[i] = *(const short8*)&Ac[ar_ + 8192 + (4 + i) * 512];
    if (stage) {
      #pragma unroll
      for (int j = 0; j < 4; ++j)
        *(short8*)&As[cb ^ 1][awoff[j]] = cvt8(av[2 * j], av[2 * j + 1]);
    }
    __builtin_amdgcn_s_barrier();
    LGKM0
    MCL(4, af, bf)
    asm volatile("s_waitcnt vmcnt(0) lgkmcnt(0)" ::: "memory");
    __builtin_amdgcn_s_barrier();
  }
  const int lgrp = lane >> 4;
  const int lc = lane & 15;
  float vah[4];
  #pragma unroll
  for (int n = 0; n < 4; ++n) vah[n] = va[h0 + wn * 64 + n * 16 + lc];
  #pragma unroll
  for (int m = 0; m < 8; ++m) {
    #pragma unroll
    for (int reg = 0; reg < 4; ++reg) {
      int row = wm * 128 + m * 16 + lgrp * 4 + reg;
      int r = r0 + row;
      int bb = r & (B_ - 1);
      const float* wrow = wqb + bb * H_ + h0 + wn * 64 + lc;
      float s = 0.f;
      #pragma unroll
      for (int n = 0; n < 4; ++n)
        s += vah[n] * fast_tanh(acc[m][n][reg] + wrow[n * 16]);
      s += __shfl_xor(s, 1);
      s += __shfl_xor(s, 2);
      s += __shfl_xor(s, 4);
      s += __shfl_xor(s, 8);
      if (lc == 0) scores_p[(size_t)r * 16 + nt * 4 + wn] = s;
    }
  }
}

// ---------------- kernel 4: reduce 16 partials + softmax -> weights ----------------
__global__ void k_softmax(const float* __restrict__ scores_p, float* __restrict__ out) {
  int b = blockIdx.x;
  int t = threadIdx.x;
  __shared__ float sc[S_];
  __shared__ float red[4];
  float lmax = -3.4e38f;
  #pragma unroll
  for (int i = 0; i < 8; ++i) {
    int s = t + i * 256;
    const float* p = scores_p + ((size_t)s * B_ + b) * 16;
    f32x4 p0 = *(const f32x4*)p;
    f32x4 p1 = *(const f32x4*)(p + 4);
    f32x4 p2 = *(const f32x4*)(p + 8);
    f32x4 p3 = *(const f32x4*)(p + 12);
    f32x4 ps = p0 + p1 + p2 + p3;
    float v = ps.x + ps.y + ps.z + ps.w;
    sc[s] = v;
    lmax = fmaxf(lmax, v);
  }
  #pragma unroll
  for (int o = 32; o >= 1; o >>= 1) lmax = fmaxf(lmax, __shfl_xor(lmax, o));
  if ((t & 63) == 0) red[t >> 6] = lmax;
  __syncthreads();
  float gmax = fmaxf(fmaxf(red[0], red[1]), fmaxf(red[2], red[3]));
  __syncthreads();
  float lsum = 0.f;
  #pragma unroll
  for (int i = 0; i < 8; ++i) {
    int s = t + i * 256;
    float e = __builtin_amdgcn_exp2f((sc[s] - gmax) * 1.4426950408889634f);
    sc[s] = e;
    lsum += e;
  }
  #pragma unroll
  for (int o = 32; o >= 1; o >>= 1) lsum += __shfl_xor(lsum, o);
  if ((t & 63) == 0) red[t >> 6] = lsum;
  __syncthreads();
  float inv = 1.0f / (red[0] + red[1] + red[2] + red[3]);
  for (int i = 0; i < 8; ++i) {
    int s = t + i * 256;
    out[(size_t)65536 + b * S_ + s] = sc[s] * inv;
  }
}

// ---------------- kernel 5: context partials (coalesced f32 keys) ----------------
__global__ void k_ctx_partial(const float* __restrict__ keys, const float* __restrict__ wts,
                              float* __restrict__ cp) {
  int b = blockIdx.x;
  int dc = blockIdx.y;
  int scn = blockIdx.z;
  int t = threadIdx.x;
  __shared__ float wl[256];
  int s0 = scn * 256;
  wl[t] = wts[b * S_ + s0 + t];
  __syncthreads();
  int d = dc * 1024 + t * 4;
  f32x4 acc = {};
  #pragma unroll 4
  for (int i = 0; i < 256; ++i) {
    int s = s0 + i;
    f32x4 kv = *(const f32x4*)(keys + ((size_t)s * B_ + b) * D2_ + d);
    acc += kv * wl[i];
  }
  *(f32x4*)(cp + ((size_t)scn * B_ + b) * D2_ + d) = acc;
}

// ---------------- kernel 6: reduce context partials ----------------
__global__ void k_ctx_reduce(const float* __restrict__ cp, float* __restrict__ out) {
  int i = blockIdx.x * 256 + threadIdx.x;
  float s = 0.f;
  #pragma unroll
  for (int j = 0; j < 8; ++j) s += cp[(size_t)j * 65536 + i];
  out[i] = s;
}

extern "C" void kernel_launch(void* const* d_in, const int* in_sizes, int n_in,
                              void* d_out, int out_size, void* d_ws, size_t ws_size,
                              hipStream_t stream) {
  const float* query = (const float*)d_in[0];
  const float* keys  = (const float*)d_in[1];
  const float* Wa_w  = (const float*)d_in[2];
  const float* Wa_b  = (const float*)d_in[3];
  const float* Ua_w  = (const float*)d_in[4];
  const float* Ua_b  = (const float*)d_in[5];
  const float* Va_w  = (const float*)d_in[6];
  // Va_b (d_in[7]) intentionally unused: softmax is shift-invariant.
  float* out = (float*)d_out;
  char* ws = (char*)d_ws;

  const size_t KEYS_BF_BYTES = 268435456ull;  // 256 MiB
  const size_t TAIL = 16ull * 1024 * 1024;    // uab 4M + wqb 128K + sp 4M + cp 2M + pad
  bool big = ws_size >= KEYS_BF_BYTES + TAIL;

  if (big) {
    short* keys_bf = (short*)ws;
    char* base = ws + KEYS_BF_BYTES;
    short* uab_t = (short*)(base);
    float* wqb = (float*)(base + 4u * 1024 * 1024);
    float* sp  = (float*)(base + 4u * 1024 * 1024 + 128 * 1024);
    float* cp  = (float*)(base + 8u * 1024 * 1024 + 256 * 1024);

    hipLaunchKernelGGL(k_convert_ua, dim3(1024), dim3(256), 0, stream, Ua_w, uab_t);
    hipLaunchKernelGGL(k_convert_keys, dim3(65536), dim3(256), 0, stream, keys, keys_bf);
    hipLaunchKernelGGL(k_wq, dim3(32, 8), dim3(256), 0, stream, query, Wa_w, Wa_b, Ua_b, wqb);
    hipLaunchKernelGGL(k_gemm_score, dim3(1024), dim3(512), 0, stream, keys_bf, uab_t, wqb, Va_w, sp);
    hipLaunchKernelGGL(k_softmax, dim3(32), dim3(256), 0, stream, sp, out);
    hipLaunchKernelGGL(k_ctx_partial, dim3(32, 2, 8), dim3(256), 0, stream, keys, out + 65536, cp);
    hipLaunchKernelGGL(k_ctx_reduce, dim3(256), dim3(256), 0, stream, cp, out);
  } else {
    short* uab_t = (short*)(ws);
    float* wqb = (float*)(ws + 4u * 1024 * 1024);
    float* sp  = (float*)(ws + 4u * 1024 * 1024 + 128 * 1024);
    float* cp  = (float*)(ws + 8u * 1024 * 1024 + 256 * 1024);

    hipLaunchKernelGGL(k_convert_ua, dim3(1024), dim3(256), 0, stream, Ua_w, uab_t);
    hipLaunchKernelGGL(k_wq, dim3(32, 8), dim3(256), 0, stream, query, Wa_w, Wa_b, Ua_b, wqb);
    hipLaunchKernelGGL(k_gemm_rs, dim3(1024), dim3(512), 0, stream, keys, uab_t, wqb, Va_w, sp);
    hipLaunchKernelGGL(k_softmax, dim3(32), dim3(256), 0, stream, sp, out);
    hipLaunchKernelGGL(k_ctx_partial, dim3(32, 2, 8), dim3(256), 0, stream, keys, out + 65536, cp);
    hipLaunchKernelGGL(k_ctx_reduce, dim3(256), dim3(256), 0, stream, cp, out);
  }
}

// Round 8
// 507.779 us; speedup vs baseline: 1.0935x; 1.0935x over previous
//
#include <hip/hip_runtime.h>
#include <hip/hip_bf16.h>

typedef __attribute__((ext_vector_type(4))) float f32x4;
typedef __attribute__((ext_vector_type(8))) short short8;

#define B_   32
#define S_   2048
#define H_   1024
#define D2_  2048   // 2H
#define BM   256
#define BN   256
#define BK   64
#define NKT  32        // D2_/BK
#define TILE_SH 16384  // shorts per 256x64 tile (32 KB)

// In-tile layout (keys_bf, uab_t): 256 rows x 8 slots x 16B; slot s' holds source
// k-quarter q = s' ^ (row&7); global k = kt*64 + q*8 + e.

// RNE f32 -> bf16
__device__ __forceinline__ short f2bf(float f) {
  unsigned u = __float_as_uint(f);
  u = (u + 0x7fffu + ((u >> 16) & 1u)) >> 16;
  return (short)u;
}

__device__ __forceinline__ float bf2f(short s) {
  return __uint_as_float(((unsigned)(unsigned short)s) << 16);
}

__device__ __forceinline__ short8 cvt8(f32x4 a, f32x4 b) {
  short8 o;
  o[0] = f2bf(a.x); o[1] = f2bf(a.y); o[2] = f2bf(a.z); o[3] = f2bf(a.w);
  o[4] = f2bf(b.x); o[5] = f2bf(b.y); o[6] = f2bf(b.z); o[7] = f2bf(b.w);
  return o;
}

// tanh via hardware exp2: tanh(x) = 1 - 2/(2^(2x*log2e)+1). Correct limits at +-inf.
__device__ __forceinline__ float fast_tanh(float x) {
  float e = __builtin_amdgcn_exp2f(x * 2.885390081777927f);
  return 1.0f - 2.0f * __builtin_amdgcn_rcpf(e + 1.0f);
}

__device__ __forceinline__ void gload16(const short* g, short* l) {
  __builtin_amdgcn_global_load_lds((const __attribute__((address_space(1))) void*)g,
                                   (__attribute__((address_space(3))) void*)l, 16, 0, 0);
}

// ---------------- kernel 1a: Ua_w f32 -> bf16 tile image ([nt(4)][kt(32)] tiles) ----------------
__global__ void k_convert_ua(const float* __restrict__ src, short* __restrict__ dst) {
  int idx = blockIdx.x * 256 + threadIdx.x;    // 262144 x 16B units
  int wu  = idx & 2047;
  int kt  = (idx >> 11) & 31;
  int nt  = idx >> 16;
  int row = wu >> 3;
  int sl  = wu & 7;
  int q   = sl ^ (row & 7);
  const float* s = src + (size_t)(nt * 256 + row) * D2_ + kt * 64 + q * 8;
  f32x4 a = *(const f32x4*)s;
  f32x4 b = *(const f32x4*)(s + 4);
  *(short8*)(dst + (size_t)idx * 8) = cvt8(a, b);
}

// ---------------- kernel 1b: keys f32 -> bf16 tile image ([mt(256)][kt(32)] tiles) ----------------
__global__ void k_convert_keys(const float* __restrict__ src, short* __restrict__ dst) {
  int idx = blockIdx.x * 256 + threadIdx.x;    // 16777216 x 16B units (grid 65536)
  int wu  = idx & 2047;
  int kt  = (idx >> 11) & 31;
  int mt  = idx >> 16;                         // 0..255
  int row = wu >> 3;
  int sl  = wu & 7;
  int q   = sl ^ (row & 7);
  const float* s = src + (size_t)(mt * 256 + row) * D2_ + kt * 64 + q * 8;
  f32x4 a = *(const f32x4*)s;
  f32x4 b = *(const f32x4*)(s + 4);
  *(short8*)(dst + (size_t)idx * 8) = cvt8(a, b);
}

// ---------------- kernel 2: wqb[b][h] = q[b] . Wa_w[h] + Wa_b[h] + Ua_b[h] ----------------
__global__ void k_wq(const float* __restrict__ query, const float* __restrict__ Wa_w,
                     const float* __restrict__ Wa_b, const float* __restrict__ Ua_b,
                     float* __restrict__ wqb) {
  int b = blockIdx.x;       // 32
  int hc = blockIdx.y;      // 8
  int t = threadIdx.x;      // 256
  __shared__ float q[H_];
  for (int i = t; i < H_; i += 256) q[i] = query[(size_t)b * (4 * H_) + 3 * H_ + i];
  __syncthreads();
  int h = hc * 128 + (t >> 1);
  int kh = (t & 1) * 512;
  const float* wr = Wa_w + (size_t)h * H_ + kh;
  float acc = 0.f;
  #pragma unroll 8
  for (int k = 0; k < 512; k += 4) {
    f32x4 wv = *(const f32x4*)(wr + k);
    acc += wv.x * q[kh + k] + wv.y * q[kh + k + 1] + wv.z * q[kh + k + 2] + wv.w * q[kh + k + 3];
  }
  acc += __shfl_xor(acc, 1);
  if ((t & 1) == 0) wqb[b * H_ + h] = acc + Wa_b[h] + Ua_b[h];
}

// ---------------- kernel 3: fused GEMM (keys @ Ua^T) + tanh + Va-reduce ----------------
// (R5-measured best variant: 4 phases, strict alternation, per-tile drain.)
#define AF_READ(mA, mB)                                         \
  af[0] = *(const short8*)&Ac[aread0 + (mA) * 1024];            \
  af[1] = *(const short8*)&Ac[aread1 + (mA) * 1024];            \
  af[2] = *(const short8*)&Ac[aread0 + (mB) * 1024];            \
  af[3] = *(const short8*)&Ac[aread1 + (mB) * 1024];

#define MFMA16(mA, mB)                                                                            \
  __builtin_amdgcn_s_setprio(1);                                                                  \
  _Pragma("unroll")                                                                               \
  for (int n = 0; n < 4; ++n) {                                                                   \
    acc[mA][n] = __builtin_amdgcn_mfma_f32_16x16x32_bf16(af[0], bf[2*n],   acc[mA][n], 0, 0, 0);  \
    acc[mA][n] = __builtin_amdgcn_mfma_f32_16x16x32_bf16(af[1], bf[2*n+1], acc[mA][n], 0, 0, 0);  \
    acc[mB][n] = __builtin_amdgcn_mfma_f32_16x16x32_bf16(af[2], bf[2*n],   acc[mB][n], 0, 0, 0);  \
    acc[mB][n] = __builtin_amdgcn_mfma_f32_16x16x32_bf16(af[3], bf[2*n+1], acc[mB][n], 0, 0, 0);  \
  }                                                                                               \
  __builtin_amdgcn_s_setprio(0);

#define STAGE4(src_, dst_)                         \
  gload16((src_) + 0 * 4096, (dst_) + 0 * 4096 + wu); \
  gload16((src_) + 1 * 4096, (dst_) + 1 * 4096 + wu); \
  gload16((src_) + 2 * 4096, (dst_) + 2 * 4096 + wu); \
  gload16((src_) + 3 * 4096, (dst_) + 3 * 4096 + wu);

__global__ __launch_bounds__(512, 2) void k_gemm_score(
    const short* __restrict__ keys_bf, const short* __restrict__ uab_t,
    const float* __restrict__ wqb, const float* __restrict__ va,
    float* __restrict__ scores_p) {
  __shared__ short As[2][TILE_SH];   // 2 x 32 KB
  __shared__ short Bs[2][TILE_SH];   // 2 x 32 KB

  // bijective XCD swizzle: the 4 nt-blocks of an mt adjacent on one XCD
  const int bid = blockIdx.x;
  const int g = (bid & 7) * 128 + (bid >> 3);
  const int mt = g >> 2;               // 0..255
  const int nt = g & 3;                // 0..3
  const int r0 = mt * BM;
  const int h0 = nt * BN;

  const int t = threadIdx.x;
  const int lane = t & 63;
  const int w = t >> 6;
  const int wm = w >> 2;               // 0..1 (128-row half)
  const int wn = w & 3;                // 0..3 (64-col quarter)

  f32x4 acc[8][4] = {};

  const short* abase = keys_bf + (size_t)mt * (NKT * TILE_SH) + t * 8;
  const short* bbase = uab_t  + (size_t)nt * (NKT * TILE_SH) + t * 8;
  const int wu = w * 512;              // wave-uniform shorts within a 4096-short batch

  // fragment read offsets (shorts); row&7 == (lane&15)&7 for 16-row frags
  const int lr = lane & 15;
  const int lq = lane >> 4;
  const int sl0 = lq ^ (lr & 7);
  const int aread0 = (wm * 128 + lr) * 64 + sl0 * 8;
  const int aread1 = aread0 ^ 32;      // slot ^4  (ksub=1)
  const int bread0 = (wn * 64 + lr) * 64 + sl0 * 8;
  const int bread1 = bread0 ^ 32;

  // ---- prologue: stage tile 0 ----
  {
    STAGE4(abase, &As[0][0])
    STAGE4(bbase, &Bs[0][0])
    asm volatile("s_waitcnt vmcnt(0)" ::: "memory");
    __builtin_amdgcn_s_barrier();
  }

  #pragma unroll 1
  for (int kt = 0; kt < NKT; ++kt) {
    const int cb = kt & 1;
    const bool stage = (kt < NKT - 1);
    const short* Ac = As[cb];
    const short* Bc = Bs[cb];
    const short* anext = abase + (size_t)(kt + 1) * TILE_SH;
    const short* bnext = bbase + (size_t)(kt + 1) * TILE_SH;
    short* Anb = &As[cb ^ 1][0];
    short* Bnb = &Bs[cb ^ 1][0];
    short8 bf[8], af[4];

    // ---------- P0: all B frags + A frags m0,m1; issue next A stage ----------
    #pragma unroll
    for (int n = 0; n < 4; ++n) {
      bf[2 * n]     = *(const short8*)&Bc[bread0 + n * 1024];
      bf[2 * n + 1] = *(const short8*)&Bc[bread1 + n * 1024];
    }
    AF_READ(0, 1)
    if (stage) { STAGE4(anext, Anb) }
    __builtin_amdgcn_s_barrier();
    asm volatile("s_waitcnt lgkmcnt(0)" ::: "memory");
    MFMA16(0, 1)
    __builtin_amdgcn_s_barrier();

    // ---------- P1: A frags m2,m3; issue next B stage ----------
    AF_READ(2, 3)
    if (stage) { STAGE4(bnext, Bnb) }
    __builtin_amdgcn_s_barrier();
    asm volatile("s_waitcnt lgkmcnt(0)" ::: "memory");
    MFMA16(2, 3)
    __builtin_amdgcn_s_barrier();

    // ---------- P2: A frags m4,m5 ----------
    AF_READ(4, 5)
    __builtin_amdgcn_s_barrier();
    asm volatile("s_waitcnt lgkmcnt(0)" ::: "memory");
    MFMA16(4, 5)
    __builtin_amdgcn_s_barrier();

    // ---------- P3: A frags m6,m7; drain staging before buffer flip ----------
    AF_READ(6, 7)
    __builtin_amdgcn_s_barrier();
    asm volatile("s_waitcnt lgkmcnt(0)" ::: "memory");
    MFMA16(6, 7)
    asm volatile("s_waitcnt vmcnt(0)" ::: "memory");
    __builtin_amdgcn_s_barrier();
  }

  // ---- epilogue: tanh + Va-weighted row-reduce ----
  // C/D layout: col = lane&15, row = (lane>>4)*4 + reg
  const int lgrp = lane >> 4;
  const int lc = lane & 15;
  float vah[4];
  #pragma unroll
  for (int n = 0; n < 4; ++n) vah[n] = va[h0 + wn * 64 + n * 16 + lc];
  #pragma unroll
  for (int m = 0; m < 8; ++m) {
    #pragma unroll
    for (int reg = 0; reg < 4; ++reg) {
      int row = wm * 128 + m * 16 + lgrp * 4 + reg;
      int r = r0 + row;
      int bb = r & (B_ - 1);
      const float* wrow = wqb + bb * H_ + h0 + wn * 64 + lc;
      float s = 0.f;
      #pragma unroll
      for (int n = 0; n < 4; ++n)
        s += vah[n] * fast_tanh(acc[m][n][reg] + wrow[n * 16]);
      s += __shfl_xor(s, 1);
      s += __shfl_xor(s, 2);
      s += __shfl_xor(s, 4);
      s += __shfl_xor(s, 8);
      if (lc == 0) scores_p[(size_t)r * 16 + nt * 4 + wn] = s;
    }
  }
}

// ---------------- fallback GEMM (reg-staged A; used when ws too small) ----------------
__global__ __launch_bounds__(512, 2) void k_gemm_rs(
    const float* __restrict__ keys, const short* __restrict__ uab_t,
    const float* __restrict__ wqb, const float* __restrict__ va,
    float* __restrict__ scores_p) {
  __shared__ short As[2][TILE_SH];
  __shared__ short Bs[2][TILE_SH];
  const int bid = blockIdx.x;
  const int g = (bid & 7) * 128 + (bid >> 3);
  const int mt = g >> 2;
  const int nt = g & 3;
  const int r0 = mt * BM;
  const int h0 = nt * BN;
  const int t = threadIdx.x;
  const int lane = t & 63;
  const int w = t >> 6;
  const int wm = w >> 2;
  const int wn = w & 3;
  f32x4 acc[8][4] = {};
  const int arow = t >> 1;
  const int ahalf = t & 1;
  const float* abase = keys + (size_t)(r0 + arow) * D2_ + ahalf * 32;
  int awoff[4];
  #pragma unroll
  for (int j = 0; j < 4; ++j)
    awoff[j] = arow * 64 + ((((ahalf << 2) | j) ^ (arow & 7)) << 3);
  const short* bbase = uab_t + (size_t)nt * NKT * TILE_SH + t * 8;
  const int wu = w * 512;
  const int lr = lane & 15;
  const int lq = lane >> 4;
  const int sl0 = lq ^ (lr & 7);
  const int aread0 = (wm * 128 + lr) * 64 + sl0 * 8;
  const int aread1 = aread0 ^ 32;
  const int bread0 = (wn * 64 + lr) * 64 + sl0 * 8;
  const int bread1 = bread0 ^ 32;
  {
    f32x4 v[8];
    #pragma unroll
    for (int j = 0; j < 8; ++j) v[j] = *(const f32x4*)(abase + j * 4);
    #pragma unroll
    for (int j = 0; j < 4; ++j)
      *(short8*)&As[0][awoff[j]] = cvt8(v[2 * j], v[2 * j + 1]);
    STAGE4(bbase, &Bs[0][0])
    asm volatile("s_waitcnt vmcnt(0) lgkmcnt(0)" ::: "memory");
    __builtin_amdgcn_s_barrier();
  }
  f32x4 av[8];
  #pragma unroll 1
  for (int kt = 0; kt < NKT; ++kt) {
    const int cb = kt & 1;
    const bool stage = (kt < NKT - 1);
    const float* anext = abase + (kt + 1) * BK;
    const short* bnext = bbase + (size_t)(kt + 1) * TILE_SH;
    short* Bnb = &Bs[cb ^ 1][0];
    const short* Ac = As[cb];
    const short* Bc = Bs[cb];
    short8 bf[8], af[4];
    #pragma unroll
    for (int n = 0; n < 4; ++n) {
      bf[2 * n]     = *(const short8*)&Bc[bread0 + n * 1024];
      bf[2 * n + 1] = *(const short8*)&Bc[bread1 + n * 1024];
    }
    AF_READ(0, 1)
    if (stage) {
      #pragma unroll
      for (int j = 0; j < 8; ++j) av[j] = *(const f32x4*)(anext + j * 4);
    }
    __builtin_amdgcn_s_barrier();
    asm volatile("s_waitcnt lgkmcnt(0)" ::: "memory");
    MFMA16(0, 1)
    __builtin_amdgcn_s_barrier();
    AF_READ(2, 3)
    if (stage) {
      gload16(bnext + 0 * 4096, Bnb + 0 * 4096 + wu);
      gload16(bnext + 1 * 4096, Bnb + 1 * 4096 + wu);
    }
    __builtin_amdgcn_s_barrier();
    asm volatile("s_waitcnt lgkmcnt(0)" ::: "memory");
    MFMA16(2, 3)
    __builtin_amdgcn_s_barrier();
    AF_READ(4, 5)
    if (stage) {
      gload16(bnext + 2 * 4096, Bnb + 2 * 4096 + wu);
      gload16(bnext + 3 * 4096, Bnb + 3 * 4096 + wu);
    }
    __builtin_amdgcn_s_barrier();
    asm volatile("s_waitcnt lgkmcnt(0)" ::: "memory");
    MFMA16(4, 5)
    __builtin_amdgcn_s_barrier();
    AF_READ(6, 7)
    if (stage) {
      #pragma unroll
      for (int j = 0; j < 4; ++j)
        *(short8*)&As[cb ^ 1][awoff[j]] = cvt8(av[2 * j], av[2 * j + 1]);
    }
    __builtin_amdgcn_s_barrier();
    asm volatile("s_waitcnt lgkmcnt(0)" ::: "memory");
    MFMA16(6, 7)
    asm volatile("s_waitcnt vmcnt(0) lgkmcnt(0)" ::: "memory");
    __builtin_amdgcn_s_barrier();
  }
  const int lgrp = lane >> 4;
  const int lc = lane & 15;
  float vah[4];
  #pragma unroll
  for (int n = 0; n < 4; ++n) vah[n] = va[h0 + wn * 64 + n * 16 + lc];
  #pragma unroll
  for (int m = 0; m < 8; ++m) {
    #pragma unroll
    for (int reg = 0; reg < 4; ++reg) {
      int row = wm * 128 + m * 16 + lgrp * 4 + reg;
      int r = r0 + row;
      int bb = r & (B_ - 1);
      const float* wrow = wqb + bb * H_ + h0 + wn * 64 + lc;
      float s = 0.f;
      #pragma unroll
      for (int n = 0; n < 4; ++n)
        s += vah[n] * fast_tanh(acc[m][n][reg] + wrow[n * 16]);
      s += __shfl_xor(s, 1);
      s += __shfl_xor(s, 2);
      s += __shfl_xor(s, 4);
      s += __shfl_xor(s, 8);
      if (lc == 0) scores_p[(size_t)r * 16 + nt * 4 + wn] = s;
    }
  }
}

// ---------------- kernel 4: reduce 16 partials + softmax -> weights ----------------
__global__ void k_softmax(const float* __restrict__ scores_p, float* __restrict__ out) {
  int b = blockIdx.x;
  int t = threadIdx.x;
  __shared__ float sc[S_];
  __shared__ float red[4];
  float lmax = -3.4e38f;
  #pragma unroll
  for (int i = 0; i < 8; ++i) {
    int s = t + i * 256;
    const float* p = scores_p + ((size_t)s * B_ + b) * 16;
    f32x4 p0 = *(const f32x4*)p;
    f32x4 p1 = *(const f32x4*)(p + 4);
    f32x4 p2 = *(const f32x4*)(p + 8);
    f32x4 p3 = *(const f32x4*)(p + 12);
    f32x4 ps = p0 + p1 + p2 + p3;
    float v = ps.x + ps.y + ps.z + ps.w;
    sc[s] = v;
    lmax = fmaxf(lmax, v);
  }
  #pragma unroll
  for (int o = 32; o >= 1; o >>= 1) lmax = fmaxf(lmax, __shfl_xor(lmax, o));
  if ((t & 63) == 0) red[t >> 6] = lmax;
  __syncthreads();
  float gmax = fmaxf(fmaxf(red[0], red[1]), fmaxf(red[2], red[3]));
  __syncthreads();
  float lsum = 0.f;
  #pragma unroll
  for (int i = 0; i < 8; ++i) {
    int s = t + i * 256;
    float e = __builtin_amdgcn_exp2f((sc[s] - gmax) * 1.4426950408889634f);
    sc[s] = e;
    lsum += e;
  }
  #pragma unroll
  for (int o = 32; o >= 1; o >>= 1) lsum += __shfl_xor(lsum, o);
  if ((t & 63) == 0) red[t >> 6] = lsum;
  __syncthreads();
  float inv = 1.0f / (red[0] + red[1] + red[2] + red[3]);
  for (int i = 0; i < 8; ++i) {
    int s = t + i * 256;
    out[(size_t)65536 + b * S_ + s] = sc[s] * inv;
  }
}

// ---------------- kernel 5 (big path): ctx partials from bf16 tiles, coalesced ----------------
// Grid (kt=32, mtc=16). Block reads 16 whole tiles at fixed kt linearly (512 KB).
// Thread (cg=t>>5, b=t&31) owns cols kt*64+cg*8..+7; per (c,s8) reads one 16B unit at
// row = s8*32+b, slot = cg ^ (b&7) (row&7 == b&7). Weights read from L2-hot global.
__global__ __launch_bounds__(256) void k_ctx_partial_bf2(const short* __restrict__ keys_bf,
                                                         const float* __restrict__ wts,
                                                         float* __restrict__ cp) {
  const int kt = blockIdx.x;    // 32
  const int mtc = blockIdx.y;   // 16
  const int t = threadIdx.x;    // 256
  const int cg = t >> 5;        // 0..7
  const int b = t & 31;
  const int slot = cg ^ (b & 7);
  const float* wbase = wts + (size_t)b * S_ + mtc * 128;
  f32x4 accA = {}, accB = {};
  #pragma unroll 2
  for (int c = 0; c < 16; ++c) {
    const short* tb = keys_bf + ((size_t)((mtc * 16 + c) * 32 + kt)) * TILE_SH + (slot << 3);
    f32x4 w0 = *(const f32x4*)(wbase + c * 8);
    f32x4 w1 = *(const f32x4*)(wbase + c * 8 + 4);
    float wg[8] = {w0.x, w0.y, w0.z, w0.w, w1.x, w1.y, w1.z, w1.w};
    #pragma unroll
    for (int s8 = 0; s8 < 8; ++s8) {
      short8 v = *(const short8*)(tb + (s8 * 32 + b) * 64);
      float wgt = wg[s8];
      accA.x += wgt * bf2f(v[0]); accA.y += wgt * bf2f(v[1]);
      accA.z += wgt * bf2f(v[2]); accA.w += wgt * bf2f(v[3]);
      accB.x += wgt * bf2f(v[4]); accB.y += wgt * bf2f(v[5]);
      accB.z += wgt * bf2f(v[6]); accB.w += wgt * bf2f(v[7]);
    }
  }
  float* o = cp + ((size_t)mtc * B_ + b) * D2_ + kt * 64 + cg * 8;
  *(f32x4*)o = accA;
  *(f32x4*)(o + 4) = accB;
}

// ---------------- kernel 5 (fallback): ctx partials from f32 keys ----------------
__global__ void k_ctx_partial(const float* __restrict__ keys, const float* __restrict__ wts,
                              float* __restrict__ cp) {
  int b = blockIdx.x;
  int dc = blockIdx.y;
  int scn = blockIdx.z;
  int t = threadIdx.x;
  __shared__ float wl[256];
  int s0 = scn * 256;
  wl[t] = wts[b * S_ + s0 + t];
  __syncthreads();
  int d = dc * 1024 + t * 4;
  f32x4 acc = {};
  #pragma unroll 4
  for (int i = 0; i < 256; ++i) {
    int s = s0 + i;
    f32x4 kv = *(const f32x4*)(keys + ((size_t)s * B_ + b) * D2_ + d);
    acc += kv * wl[i];
  }
  *(f32x4*)(cp + ((size_t)scn * B_ + b) * D2_ + d) = acc;
}

// ---------------- kernel 6: reduce context partials ----------------
__global__ void k_ctx_reduce(const float* __restrict__ cp, float* __restrict__ out, int np) {
  int i = blockIdx.x * 256 + threadIdx.x;
  float s = 0.f;
  for (int j = 0; j < np; ++j) s += cp[(size_t)j * 65536 + i];
  out[i] = s;
}

extern "C" void kernel_launch(void* const* d_in, const int* in_sizes, int n_in,
                              void* d_out, int out_size, void* d_ws, size_t ws_size,
                              hipStream_t stream) {
  const float* query = (const float*)d_in[0];
  const float* keys  = (const float*)d_in[1];
  const float* Wa_w  = (const float*)d_in[2];
  const float* Wa_b  = (const float*)d_in[3];
  const float* Ua_w  = (const float*)d_in[4];
  const float* Ua_b  = (const float*)d_in[5];
  const float* Va_w  = (const float*)d_in[6];
  // Va_b (d_in[7]) intentionally unused: softmax is shift-invariant.
  float* out = (float*)d_out;
  char* ws = (char*)d_ws;

  const size_t KEYS_BF_BYTES = 268435456ull;  // 256 MiB
  const size_t TAIL = 16ull * 1024 * 1024;    // uab 4M + wqb 128K + sp 4M + cp 4M + pad
  bool big = ws_size >= KEYS_BF_BYTES + TAIL;

  if (big) {
    short* keys_bf = (short*)ws;
    char* base = ws + KEYS_BF_BYTES;
    short* uab_t = (short*)(base);
    float* wqb = (float*)(base + 4u * 1024 * 1024);
    float* sp  = (float*)(base + 4u * 1024 * 1024 + 128 * 1024);
    float* cp  = (float*)(base + 8u * 1024 * 1024 + 256 * 1024);   // 4 MB (16 partials)

    hipLaunchKernelGGL(k_convert_ua, dim3(1024), dim3(256), 0, stream, Ua_w, uab_t);
    hipLaunchKernelGGL(k_convert_keys, dim3(65536), dim3(256), 0, stream, keys, keys_bf);
    hipLaunchKernelGGL(k_wq, dim3(32, 8), dim3(256), 0, stream, query, Wa_w, Wa_b, Ua_b, wqb);
    hipLaunchKernelGGL(k_gemm_score, dim3(1024), dim3(512), 0, stream, keys_bf, uab_t, wqb, Va_w, sp);
    hipLaunchKernelGGL(k_softmax, dim3(32), dim3(256), 0, stream, sp, out);
    hipLaunchKernelGGL(k_ctx_partial_bf2, dim3(32, 16), dim3(256), 0, stream, keys_bf, out + 65536, cp);
    hipLaunchKernelGGL(k_ctx_reduce, dim3(256), dim3(256), 0, stream, cp, out, 16);
  } else {
    short* uab_t = (short*)(ws);
    float* wqb = (float*)(ws + 4u * 1024 * 1024);
    float* sp  = (float*)(ws + 4u * 1024 * 1024 + 128 * 1024);
    float* cp  = (float*)(ws + 8u * 1024 * 1024 + 256 * 1024);

    hipLaunchKernelGGL(k_convert_ua, dim3(1024), dim3(256), 0, stream, Ua_w, uab_t);
    hipLaunchKernelGGL(k_wq, dim3(32, 8), dim3(256), 0, stream, query, Wa_w, Wa_b, Ua_b, wqb);
    hipLaunchKernelGGL(k_gemm_rs, dim3(1024), dim3(512), 0, stream, keys, uab_t, wqb, Va_w, sp);
    hipLaunchKernelGGL(k_softmax, dim3(32), dim3(256), 0, stream, sp, out);
    hipLaunchKernelGGL(k_ctx_partial, dim3(32, 2, 8), dim3(256), 0, stream, keys, out + 65536, cp);
    hipLaunchKernelGGL(k_ctx_reduce, dim3(256), dim3(256), 0, stream, cp, out, 8);
  }
}